// Round 14
// baseline (732.067 us; speedup 1.0000x reference)
//
#include <hip/hip_runtime.h>

typedef unsigned int uint;

#define N_NODES 1000000
#define D       128
#define T_STEPS 100
#define B       1024
#define K       6
#define ALPHA   0.025f

// fused kernel: 2048 blocks x 256 threads = exact full-device co-residency
// (8 blocks/CU x 256 CUs; launch_bounds(256,8) caps VGPR so 32 waves/CU fit).
// blocks [0,1280): SGD role (r9-verbatim loop, barrier among themselves only).
// blocks [1280,2048): normalizer role (pure streaming, no barriers, no waits).
#define SGDB   1280
#define NORMB  768
#define TOTB   (SGDB + NORMB)      // 2048
#define CTPB   256
#define CHUNK  10
#define NCHUNK (T_STEPS / CHUNK)   // 10 chunks, 9 rendezvous
#define CE     (CHUNK * B)         // 10240 edges per chunk
#define NWAVES (SGDB * CTPB / 64)  // 5120 SGD waves
#define EPW    (CE / NWAVES)       // 2 edges per wave per chunk
#define NNW    (NORMB * CTPB / 64) // 3072 normalizer waves

// ws layout (uint granularity):
//   barrier slot k: words [k*2048, k*2048 + SGDB), k < 10  -> 80 KB used
//   flags[r] at FLAG_OFF (N_NODES uints = 4 MB, SPARSE only)
#define FLAG_OFF     65536
#define CNT_BYTES    ((size_t)FLAG_OFF * 4)              // 256 KB
#define SPARSE_BYTES ((size_t)(FLAG_OFF + N_NODES) * 4)  // ~4.26 MB (proven r2-r11)

__device__ __forceinline__ float wave_sum(float v) {
#pragma unroll
    for (int off = 32; off; off >>= 1) v += __shfl_xor(v, off, 64);
    return v;
}

__device__ __forceinline__ uint aloadu(const uint* p) {
    return __hip_atomic_load(p, __ATOMIC_RELAXED, __HIP_MEMORY_SCOPE_AGENT);
}

// Per-chunk rendezvous among the SGD blocks (r6-r11-proven all-to-all protocol)
// + acquire fence. arrive: __syncthreads drains the block's vmcnt(0) (compiler
// emits the full s_waitcnt before s_barrier) so its scatter-atomics are
// complete at the LLC before thread0 signals its own word. wait: wave 0's
// lane j polls words {j, j+64, ...}. fence: s_waitcnt + buffer_inv drops
// clean per-XCD L2/L1 lines so next chunk's plain cached gathers observe the
// post-scatter LLC state. Each rendezvous k uses its own pre-zeroed slot.
__device__ __forceinline__ void bar_sync_acq(uint* ws_u, int k) {
    __syncthreads();
    if (threadIdx.x == 0)
        atomicAdd(&ws_u[k * 2048 + (int)blockIdx.x], 1u);
    if (threadIdx.x < 64) {
        const uint* s = ws_u + k * 2048 + threadIdx.x;
        for (;;) {
            int got = 0;
#pragma unroll
            for (int i = 0; i < SGDB / 64; ++i) got += (aloadu(s + i * 64) != 0u);
            if (got == SGDB / 64) break;
        }
    }
    __syncthreads();
    if (threadIdx.x == 0)
        __builtin_amdgcn_fence(__ATOMIC_ACQUIRE, "agent");
    __syncthreads();
}

// ---------------- prologue: flags + materialize mutable rows in `out` ----------
template <bool SPARSE>
__global__ __launch_bounds__(256) void prologue(const float* __restrict__ emb_in,
                                                const int*   __restrict__ u_idx, // [T*B]
                                                float*       __restrict__ out,
                                                uint*        __restrict__ flags)
{
    if (SPARSE) {
        const int wave = (blockIdx.x * 256 + threadIdx.x) >> 6;
        const int lane = threadIdx.x & 63;
        const int nw = gridDim.x * 4;
        for (int e = wave; e < T_STEPS * B; e += nw) {
            const int r = u_idx[e];
            if (lane == 0) flags[r] = 1u;            // dups write identical bytes
            const size_t off = (size_t)r * D + 2 * lane;
            *(float2*)(out + off) = *(const float2*)(emb_in + off);
        }
    } else {
        const int tid = blockIdx.x * 256 + threadIdx.x;
        const int stride = gridDim.x * 256;
        const float4* src = (const float4*)emb_in;
        float4*       dst = (float4*)out;
        for (int i = tid; i < N_NODES * D / 4; i += stride) dst[i] = src[i];
    }
}

// ---------------- fused: SGD loop (blocks 0..1279) + normalizer streamers ------
// SGD role is the r9 kernel verbatim (350us measured): per chunk, gather from
// chunk-start state (plain cached loads), compute err, scatter atomicAdd,
// one rendezvous + acquire fence. Normalizer role: L2-normalize the ~903K
// unflagged rows emb_in -> out. Those rows are disjoint from every SGD
// read/write (gathers of unflagged v-rows read emb_in, scatters hit flagged
// rows only), each written exactly once by one wave -> race-free in any
// schedule; normalizers never wait on anything -> deadlock-free in any
// dispatch order (worst case they just run after the SGD blocks).
template <bool SPARSE>
__global__ __launch_bounds__(CTPB, 8) void fused(const float* __restrict__ emb_in,
                                                 const int*   __restrict__ u_idx,   // [T*B]
                                                 const int*   __restrict__ tgt_idx, // [T*B*K]
                                                 float*       __restrict__ out,
                                                 uint*        ws_u)
{
    const int lane = threadIdx.x & 63;
    const uint* flags = ws_u + FLAG_OFF;  // immutable in this kernel -> cached

    if ((int)blockIdx.x >= SGDB) {
        // ---------------- normalizer role: pure HBM streaming ----------------
        if (!SPARSE) return;
        const int nwv = (((int)blockIdx.x - SGDB) * CTPB + (int)threadIdx.x) >> 6;
        const int per = (N_NODES + NNW - 1) / NNW;        // 326 rows per wave
        const int rb = nwv * per;
        const int re = (rb + per < N_NODES) ? rb + per : N_NODES;
        for (int r0 = rb; r0 < re; r0 += 8) {
            float2 v[8];
            uint   fl[8];
#pragma unroll
            for (int j = 0; j < 8; ++j) {                 // full-MLP batch
                const int r = r0 + j;
                const int ok = (r < re);
                fl[j] = ok ? flags[r] : 1u;
                v[j]  = ok ? *(const float2*)(emb_in + (size_t)r * D + 2 * lane)
                           : make_float2(0.f, 0.f);
            }
#pragma unroll
            for (int j = 0; j < 8; ++j) {
                if (fl[j] == 0u) {                        // wave-uniform predicate
                    const float ss  = wave_sum(v[j].x * v[j].x + v[j].y * v[j].y);
                    const float inv = 1.f / fmaxf(sqrtf(ss), 1e-12f);
                    *(float2*)(out + (size_t)(r0 + j) * D + 2 * lane) =
                        make_float2(v[j].x * inv, v[j].y * inv);
                }
            }
        }
        return;
    }

    // ---------------- SGD role: r9 loop verbatim -----------------------------
    const int w = ((int)blockIdx.x * CTPB + (int)threadIdx.x) >> 6; // 0..5119

    for (int c = 0; c < NCHUNK; ++c) {
        int    cu[EPW];
        float2 e2[EPW];
        {
            float2 u2l[EPW];
            float2 v2l[EPW][K];
            // gather chunk c (plain cached loads; state S(c-1) + benign
            // same-chunk fragments, r8-r11-validated)
#pragma unroll
            for (int jj = 0; jj < EPW; ++jj) {
                const int e = c * CE + w + jj * NWAVES;
                const int u = u_idx[e];
                cu[jj] = u;
                u2l[jj] = *(const float2*)(out + (size_t)u * D + 2 * lane);
#pragma unroll
                for (int k = 0; k < K; ++k) {
                    const int v = tgt_idx[e * K + k];
                    const float* src = (SPARSE && !flags[v]) ? emb_in : out;
                    v2l[jj][k] = *(const float2*)(src + (size_t)v * D + 2 * lane);
                }
            }
            // compute err
#pragma unroll
            for (int jj = 0; jj < EPW; ++jj) {
                float2 acc = make_float2(0.f, 0.f);
#pragma unroll
                for (int k = 0; k < K; ++k) {
                    const float s = wave_sum(u2l[jj].x * v2l[jj][k].x +
                                             u2l[jj].y * v2l[jj][k].y);
                    const float f = 1.f / (1.f + __expf(-s));
                    const float gg = ALPHA * ((k == 0 ? 1.f : 0.f) - f);
                    acc.x += gg * v2l[jj][k].x;
                    acc.y += gg * v2l[jj][k].y;
                }
                e2[jj] = acc;
            }
        }

        // scatter (atomicAdd at LLC: order-free accumulation)
#pragma unroll
        for (int jj = 0; jj < EPW; ++jj) {
            float* urow = out + (size_t)cu[jj] * D + 2 * lane;
            atomicAdd(urow,     e2[jj].x);
            atomicAdd(urow + 1, e2[jj].y);
        }

        if (c + 1 < NCHUNK)
            bar_sync_acq(ws_u, c);   // chunk-c scatters at LLC + caches clean
        // last chunk: kernel boundary is the barrier before the epilogue
    }
}

// ---------------- epilogue: normalize ONLY the ~97K flagged rows, in place -----
__global__ __launch_bounds__(256) void normalize_flagged(float* __restrict__ out,
                                                         const uint* __restrict__ flags)
{
    const int wave = (blockIdx.x * 256 + threadIdx.x) >> 6;
    const int lane = threadIdx.x & 63;
    const int nw = gridDim.x * 4;
    for (int r0 = wave * 4; r0 < N_NODES; r0 += nw * 4) {
        const uint4 f4 = *(const uint4*)(flags + r0);
        if (!(f4.x | f4.y | f4.z | f4.w)) continue;     // fast skip (~91%)
        const uint fl[4] = { f4.x, f4.y, f4.z, f4.w };
#pragma unroll
        for (int j = 0; j < 4; ++j) {
            if (fl[j]) {
                float2* p = (float2*)(out + (size_t)(r0 + j) * D + 2 * lane);
                const float2 v = *p;
                const float ss  = wave_sum(v.x * v.x + v.y * v.y);
                const float inv = 1.f / fmaxf(sqrtf(ss), 1e-12f);
                *p = make_float2(v.x * inv, v.y * inv);
            }
        }
    }
}

// fallback epilogue (non-sparse ws): normalize everything from the full copy
__global__ __launch_bounds__(256) void normalize_all(float* __restrict__ out)
{
    const int wave = (blockIdx.x * 256 + threadIdx.x) >> 6;
    const int lane = threadIdx.x & 63;
    const int nw = gridDim.x * 4;
    for (int r0 = wave * 4; r0 < N_NODES; r0 += nw * 4) {
#pragma unroll
        for (int j = 0; j < 4; ++j) {
            float2* p = (float2*)(out + (size_t)(r0 + j) * D + 2 * lane);
            const float2 v = *p;
            const float ss  = wave_sum(v.x * v.x + v.y * v.y);
            const float inv = 1.f / fmaxf(sqrtf(ss), 1e-12f);
            *p = make_float2(v.x * inv, v.y * inv);
        }
    }
}

extern "C" void kernel_launch(void* const* d_in, const int* in_sizes, int n_in,
                              void* d_out, int out_size, void* d_ws, size_t ws_size,
                              hipStream_t stream)
{
    const float* emb_in  = (const float*)d_in[0];
    const int*   u_idx   = (const int*)d_in[1];
    const int*   tgt_idx = (const int*)d_in[2];
    float*       out     = (float*)d_out;
    uint*        ws_u    = (uint*)d_ws;
    uint*        flags   = ws_u + FLAG_OFF;

    const bool sparse = ws_size >= SPARSE_BYTES;
    hipMemsetAsync(d_ws, 0, sparse ? SPARSE_BYTES : CNT_BYTES, stream);

    if (sparse) {
        prologue<true>   <<<1024, 256, 0, stream>>>(emb_in, u_idx, out, flags);
        fused<true>      <<<TOTB, CTPB, 0, stream>>>(emb_in, u_idx, tgt_idx, out, ws_u);
        normalize_flagged<<<2048, 256, 0, stream>>>(out, flags);
    } else {
        prologue<false>  <<<2048, 256, 0, stream>>>(emb_in, u_idx, out, flags);
        fused<false>     <<<TOTB, CTPB, 0, stream>>>(emb_in, u_idx, tgt_idx, out, ws_u);
        normalize_all    <<<2048, 256, 0, stream>>>(out);
    }
}